// Round 5
// baseline (329.181 us; speedup 1.0000x reference)
//
#include <hip/hip_runtime.h>

#define NTOK 8192
#define DDIM 1024
#define HDIM 2048
#define ODIM 1024
#define NEXP 8
#define OUTW (ODIM + NEXP)   // 1032
#define MT_MAX 64            // worst-case m-tiles per expert (all tokens -> one expert)

typedef __bf16 bf16_t;
typedef bf16_t bf16x8 __attribute__((ext_vector_type(8)));
typedef bf16_t bf16x4 __attribute__((ext_vector_type(4)));
typedef float f32x4 __attribute__((ext_vector_type(4)));

__device__ __forceinline__ void gld_lds16(bf16_t* lds, const bf16_t* g) {
  __builtin_amdgcn_global_load_lds(
      (__attribute__((address_space(1))) void*)g,
      (__attribute__((address_space(3))) void*)lds, 16, 0, 0);
}

// Per-block LDS histogram: 256 global atomics total instead of 8192.
__global__ void route_kernel(const int* __restrict__ idx, float* __restrict__ out,
                             int* __restrict__ rank, int* cnt) {
  __shared__ int lcnt[NEXP];
  __shared__ int lbase[NEXP];
  int t = threadIdx.x;
  if (t < NEXP) lcnt[t] = 0;
  __syncthreads();
  int n = blockIdx.x * 256 + t;
  int e = idx[n];
  int lr = atomicAdd(&lcnt[e], 1);
  __syncthreads();
  if (t < NEXP) lbase[t] = atomicAdd(&cnt[t], lcnt[t]);
  __syncthreads();
  rank[n] = lbase[e] + lr;
  float* o = out + (size_t)n * OUTW + ODIM;
#pragma unroll
  for (int j = 0; j < NEXP; j++) o[j] = (j == e) ? 1.0f : 0.0f;
}

// off[e] is an 8-element prefix sum; recomputed per block from cnt (L2-hot)
// instead of a dedicated 1-block scan launch.
__device__ __forceinline__ void prefix_of(const int* cnt, int e, int& base, int& count) {
  base = 0; count = 0;
#pragma unroll
  for (int j = 0; j < NEXP; j++) {
    int c = cnt[j];
    if (j < e) base += c;
    if (j == e) count = c;
  }
}

// Fused: blocks [0, NTOK) = gather (x f32 -> xg bf16, expert-sorted rows);
// blocks [NTOK, NTOK+4096) = weight transpose+convert (both W1 and W2).
// Fusing saves a launch AND makes this dispatch large enough to show up in
// the top-5 profile rows (the pre-GEMM pipeline has never been measured).
__global__ __launch_bounds__(256) void prep_kernel(
    const float* __restrict__ x, const int* __restrict__ idx,
    const int* __restrict__ rank, const int* __restrict__ cnt,
    bf16_t* __restrict__ xg, int* __restrict__ tok_of_pos,
    const float* __restrict__ s1, bf16_t* __restrict__ d1,
    const float* __restrict__ s2, bf16_t* __restrict__ d2) {
  __shared__ float t[128][65];
  int b = blockIdx.x;
  int tid = threadIdx.x;

  if (b < NTOK) {  // ---- gather ----
    int n = b;
    int e = idx[n];
    int base, count;
    prefix_of(cnt, e, base, count);
    int pos = base + rank[n];
    if (tid == 0) tok_of_pos[pos] = n;
    float4 v = ((const float4*)(x + (size_t)n * DDIM))[tid];
    bf16x4 o;
    o[0] = (bf16_t)v.x; o[1] = (bf16_t)v.y; o[2] = (bf16_t)v.z; o[3] = (bf16_t)v.w;
    *(bf16x4*)(xg + (size_t)pos * DDIM + tid * 4) = o;
    return;
  }

  // ---- wtrans: tile 128(r) x 64(c); 256B-segment reads, 16B/lane writes;
  // LDS stride 65 words -> all LDS patterns 2-way (free). ----
  b -= NTOK;
  const float* src; bf16_t* dst; int R, C, bx, by, e;
  if (b < 2048) {        // W1: C/64=32 x-tiles, R/128=8 y-tiles, 8 experts
    src = s1; dst = d1; R = DDIM; C = HDIM;
    bx = b & 31; by = (b >> 5) & 7; e = b >> 8;
  } else {               // W2: C/64=16 x-tiles, R/128=16 y-tiles, 8 experts
    int b2 = b - 2048;
    src = s2; dst = d2; R = HDIM; C = ODIM;
    bx = b2 & 15; by = (b2 >> 4) & 15; e = b2 >> 8;
  }
  int c0 = bx * 64, r0g = by * 128;
  const float* s = src + (size_t)e * R * C;
#pragma unroll
  for (int p = 0; p < 8; p++) {
    int r = (tid >> 4) + p * 16;
    int c4 = (tid & 15) * 4;
    float4 v = *(const float4*)&s[(size_t)(r0g + r) * C + c0 + c4];
    t[r][c4 + 0] = v.x;
    t[r][c4 + 1] = v.y;
    t[r][c4 + 2] = v.z;
    t[r][c4 + 3] = v.w;
  }
  __syncthreads();
  bf16_t* d = dst + (size_t)e * R * C;
  int w = tid >> 6, l = tid & 63;
#pragma unroll
  for (int itc = 0; itc < 2; itc++) {
#pragma unroll
    for (int it2 = 0; it2 < 2; it2++) {
      int c = (l >> 3) + 8 * w + 32 * itc;
      int r0 = (l & 7) * 8 + 64 * it2;
      bf16x8 o;
#pragma unroll
      for (int j = 0; j < 8; j++) o[j] = (bf16_t)t[r0 + j][c];
      *(bf16x8*)&d[(size_t)(c0 + c) * R + r0g + r0] = o;
    }
  }
}

// C[pos][n] = sum_k A[pos][k] * Bt[e][n][k] + bias[e][n]
// 1D grid, expert = blockIdx.x & 7  ->  expert pinned to one XCD.
// BK=64 (was 32): halves the number of per-K-step barrier drains; each
// vmcnt(0)+lgkmcnt(0) __syncthreads drain now amortizes over 32 MFMA.
// LDS 2x16KB = 32KB -> still 4 blocks/CU (the BK=128/64KB cliff is avoided).
// XOR swizzle (8 chunks/row): LDS slot (row, p) holds global k-eighth
// p^(row&7); staging lane loads global eighth (l&7)^(l>>3) with linear LDS
// dest (rule 21); fragment reads use slot (kh*4+q)^(mrow&7).
// Bank audit: fragment read wave = 8 lanes per 16B-slot spread over all 32
// banks, 32B/bank = wave64-b128 minimum -> conflict-free.
template <int KDIM, int NCOLS, int MTG, bool TO_BF16>
__global__ __launch_bounds__(256) void gemm_kernel(
    const bf16_t* __restrict__ A, const bf16_t* __restrict__ Bt,
    const float* __restrict__ bias,
    const int* __restrict__ cnt,
    const int* __restrict__ tok_of_pos,
    bf16_t* __restrict__ outb, float* __restrict__ outf) {
  constexpr int NT = NCOLS / 128;
  const int b = blockIdx.x;
  const int e = b & 7;
  int t = b >> 3;
  const int mtl = t % MTG;
  t /= MTG;
  const int nt = t % NT;
  const int g = t / NT;
  const int mt = g * MTG + mtl;

  int base, count;
  prefix_of(cnt, e, base, count);
  if (mt * 128 >= count) return;

  __shared__ bf16_t lA[128 * 64];   // 16 KB
  __shared__ bf16_t lB[128 * 64];   // 16 KB

  const int tid = threadIdx.x;
  const int lane = tid & 63;
  const int wave = tid >> 6;
  const int mrow = lane & 15;
  const int q = lane >> 4;
  const int wm = (wave & 1) * 64;
  const int wn = (wave >> 1) * 64;

  // staging: chunk c = wave*4+s covers tile rows c*8..c*8+7 (1KB per gld);
  // lane -> (row c*8 + l>>3, k-eighth (l&7)^(l>>3))   [XOR swizzle]
  const bf16_t* pA[4];
  const bf16_t* pB[4];
#pragma unroll
  for (int s = 0; s < 4; s++) {
    int c = wave * 4 + s;
    int lrow = c * 8 + (lane >> 3);
    int qg = (lane & 7) ^ (lane >> 3);
    int gr = base + mt * 128 + lrow;
    if (gr > NTOK - 1) gr = NTOK - 1;  // clamp: garbage rows masked at store
    pA[s] = A + (size_t)gr * KDIM + qg * 8;
    int nrow = nt * 128 + lrow;
    pB[s] = Bt + ((size_t)e * NCOLS + nrow) * KDIM + qg * 8;
  }

  f32x4 acc[4][4] = {};
  const int m7 = mrow & 7;
  const bf16_t* la0 = &lA[(wm + mrow) * 64 + ((q ^ m7) * 8)];        // kh0
  const bf16_t* la1 = &lA[(wm + mrow) * 64 + (((4 + q) ^ m7) * 8)];  // kh1
  const bf16_t* lb0 = &lB[(wn + mrow) * 64 + ((q ^ m7) * 8)];
  const bf16_t* lb1 = &lB[(wn + mrow) * 64 + (((4 + q) ^ m7) * 8)];

  for (int kk = 0; kk < KDIM; kk += 64) {
#pragma unroll
    for (int s = 0; s < 4; s++) {
      gld_lds16(&lA[(wave * 4 + s) * 512], pA[s] + kk);
      gld_lds16(&lB[(wave * 4 + s) * 512], pB[s] + kk);
    }
    __syncthreads();
    bf16x8 af[4], bfr[4];
    // k-half 0
#pragma unroll
    for (int i = 0; i < 4; i++) {
      af[i]  = *(const bf16x8*)(la0 + i * 16 * 64);
      bfr[i] = *(const bf16x8*)(lb0 + i * 16 * 64);
    }
#pragma unroll
    for (int i = 0; i < 4; i++)
#pragma unroll
      for (int j = 0; j < 4; j++)
        acc[i][j] = __builtin_amdgcn_mfma_f32_16x16x32_bf16(af[i], bfr[j], acc[i][j], 0, 0, 0);
    // k-half 1
#pragma unroll
    for (int i = 0; i < 4; i++) {
      af[i]  = *(const bf16x8*)(la1 + i * 16 * 64);
      bfr[i] = *(const bf16x8*)(lb1 + i * 16 * 64);
    }
#pragma unroll
    for (int i = 0; i < 4; i++)
#pragma unroll
      for (int j = 0; j < 4; j++)
        acc[i][j] = __builtin_amdgcn_mfma_f32_16x16x32_bf16(af[i], bfr[j], acc[i][j], 0, 0, 0);
    __syncthreads();
  }

  const int mlimit = count - mt * 128;
  float bs[4];
#pragma unroll
  for (int j = 0; j < 4; j++)
    bs[j] = bias[(size_t)e * NCOLS + nt * 128 + wn + j * 16 + mrow];

#pragma unroll
  for (int i = 0; i < 4; i++) {
#pragma unroll
    for (int r = 0; r < 4; r++) {
      int ml = wm + i * 16 + q * 4 + r;
      if (ml < mlimit) {
        int prow = base + mt * 128 + ml;
        if constexpr (TO_BF16) {
          bf16_t* orow = outb + (size_t)prow * NCOLS;
#pragma unroll
          for (int j = 0; j < 4; j++)
            orow[nt * 128 + wn + j * 16 + mrow] = (bf16_t)(acc[i][j][r] + bs[j]);
        } else {
          int tok = tok_of_pos[prow];
          float* orow = outf + (size_t)tok * OUTW;
#pragma unroll
          for (int j = 0; j < 4; j++)
            orow[nt * 128 + wn + j * 16 + mrow] = acc[i][j][r] + bs[j];
        }
      }
    }
  }
}

extern "C" void kernel_launch(void* const* d_in, const int* in_sizes, int n_in,
                              void* d_out, int out_size, void* d_ws, size_t ws_size,
                              hipStream_t stream) {
  const float* x  = (const float*)d_in[0];
  const float* W1 = (const float*)d_in[1];
  const float* b1 = (const float*)d_in[2];
  const float* W2 = (const float*)d_in[3];
  const float* b2 = (const float*)d_in[4];
  const int* idx  = (const int*)d_in[5];
  float* out = (float*)d_out;

  char* ws = (char*)d_ws;
  bf16_t* xg  = (bf16_t*)(ws);                 // 16 MB  [N][D] bf16
  bf16_t* hg  = (bf16_t*)(ws + 16777216);      // 32 MB  [N][H] bf16
  bf16_t* Wt1 = (bf16_t*)(ws + 50331648);      // 32 MB  [E][H][D] bf16
  bf16_t* Wt2 = (bf16_t*)(ws + 83886080);      // 32 MB  [E][O][H] bf16
  int* tok    = (int*)(ws + 117440512);        // 32 KB
  int* rank   = (int*)(ws + 117473280);        // 32 KB
  int* cnt    = (int*)(ws + 117506048);

  // 5 dispatches: memset, route, prep (gather+wtrans), GEMM1, GEMM2.
  hipMemsetAsync(cnt, 0, NEXP * sizeof(int), stream);
  route_kernel<<<NTOK / 256, 256, 0, stream>>>(idx, out, rank, cnt);
  prep_kernel<<<NTOK + 4096, 256, 0, stream>>>(x, idx, rank, cnt, xg, tok,
                                               W1, Wt1, W2, Wt2);
  // GEMM1: K=1024, NCOLS=2048, MTG=8 (8*128 rows * 1024 k * 2B = 2MB A-group)
  gemm_kernel<DDIM, HDIM, 8, true>
      <<<NEXP * MT_MAX * (HDIM / 128), 256, 0, stream>>>(
      xg, Wt1, b1, cnt, tok, hg, nullptr);
  // GEMM2: K=2048, NCOLS=1024, MTG=4 (4*128 rows * 2048 k * 2B = 2MB A-group)
  gemm_kernel<HDIM, ODIM, 4, false>
      <<<NEXP * MT_MAX * (ODIM / 128), 256, 0, stream>>>(
      hg, Wt2, b2, cnt, tok, nullptr, out);
}

// Round 7
// 304.841 us; speedup vs baseline: 1.0798x; 1.0798x over previous
//
#include <hip/hip_runtime.h>

#define NTOK 8192
#define DDIM 1024
#define HDIM 2048
#define ODIM 1024
#define NEXP 8
#define OUTW (ODIM + NEXP)   // 1032
#define MT_MAX 64            // worst-case m-tiles per expert
#define WT_BLKS 8192         // wtrans tiles: W1 32x16x8 + W2 16x32x8
#define GA_BLKS (NTOK / 4)   // 2048 gather blocks (4 tokens each)

typedef __bf16 bf16_t;
typedef bf16_t bf16x8 __attribute__((ext_vector_type(8)));
typedef bf16_t bf16x4 __attribute__((ext_vector_type(4)));
typedef float f32x4 __attribute__((ext_vector_type(4)));

__device__ __forceinline__ void gld_lds16(bf16_t* lds, const bf16_t* g) {
  __builtin_amdgcn_global_load_lds(
      (__attribute__((address_space(1))) void*)g,
      (__attribute__((address_space(3))) void*)lds, 16, 0, 0);
}

// Per-block LDS histogram: 256 global atomics total instead of 8192.
// (PROVEN round-4 scheme; the bcnt/no-memset variant is withdrawn until the
// container failure is explained — it extended the ws footprint.)
__global__ void route_kernel(const int* __restrict__ idx, float* __restrict__ out,
                             int* __restrict__ rank, int* cnt) {
  __shared__ int lcnt[NEXP];
  __shared__ int lbase[NEXP];
  int t = threadIdx.x;
  if (t < NEXP) lcnt[t] = 0;
  __syncthreads();
  int n = blockIdx.x * 256 + t;
  int e = idx[n];
  int lr = atomicAdd(&lcnt[e], 1);
  __syncthreads();
  if (t < NEXP) lbase[t] = atomicAdd(&cnt[t], lcnt[t]);
  __syncthreads();
  rank[n] = lbase[e] + lr;
  float* o = out + (size_t)n * OUTW + ODIM;
#pragma unroll
  for (int j = 0; j < NEXP; j++) o[j] = (j == e) ? 1.0f : 0.0f;
}

// off[e] is an 8-element prefix sum; recomputed per consumer from L2-hot cnt.
__device__ __forceinline__ void prefix_of(const int* __restrict__ cnt, int e,
                                          int& base, int& count) {
  base = 0; count = 0;
#pragma unroll
  for (int j = 0; j < NEXP; j++) {
    int c = cnt[j];
    if (j < e) base += c;
    if (j == e) count = c;
  }
}

// Fused prep. Blocks [0, WT_BLKS): weight transpose+convert, 64x64 f32 tile
// ([64][65] = 16.6KB LDS -> 8 blocks/CU; round-5's 128-row tile got 4).
// Blocks [WT_BLKS, WT_BLKS+GA_BLKS): gather, 4 tokens/block (4 independent
// float4 loads in flight per thread; round-5's 1/thread was latency-bound:
// 2.15 TB/s, VALUBusy 3%, Occupancy 33%).
__global__ __launch_bounds__(256) void prep_kernel(
    const float* __restrict__ x, const int* __restrict__ idx,
    const int* __restrict__ rank, const int* __restrict__ cnt,
    bf16_t* __restrict__ xg, int* __restrict__ tok_of_pos,
    const float* __restrict__ s1, bf16_t* __restrict__ d1,
    const float* __restrict__ s2, bf16_t* __restrict__ d2) {
  __shared__ float t[64][65];  // wtrans only (gather path never touches LDS)
  int b = blockIdx.x;
  int tid = threadIdx.x;

  if (b >= WT_BLKS) {  // ---- gather: tokens g*4 .. g*4+3 ----
    int g = b - WT_BLKS;
    float4 v[4];
    int pos[4];
#pragma unroll
    for (int ti = 0; ti < 4; ti++) {
      int n = g * 4 + ti;
      v[ti] = ((const float4*)(x + (size_t)n * DDIM))[tid];
      int e = idx[n];
      int base, cc;
      prefix_of(cnt, e, base, cc);
      pos[ti] = base + rank[n];
      if (tid == 0) tok_of_pos[pos[ti]] = n;
    }
#pragma unroll
    for (int ti = 0; ti < 4; ti++) {
      bf16x4 o;
      o[0] = (bf16_t)v[ti].x; o[1] = (bf16_t)v[ti].y;
      o[2] = (bf16_t)v[ti].z; o[3] = (bf16_t)v[ti].w;
      *(bf16x4*)(xg + (size_t)pos[ti] * DDIM + tid * 4) = o;
    }
    return;
  }

  // ---- wtrans: src [E][R][C] f32 -> dst [E][C][R] bf16, 64x64 tile ----
  // reads 256B segments; writes 128B segments; LDS stride 65 -> <=2-way (free).
  const float* src; bf16_t* dst; int R, C, bx, by, e;
  if (b < 4096) {        // W1: C=2048 (32 x-tiles), R=1024 (16 y-tiles)
    src = s1; dst = d1; R = DDIM; C = HDIM;
    bx = b & 31; by = (b >> 5) & 15; e = b >> 9;
  } else {               // W2: C=1024 (16 x-tiles), R=2048 (32 y-tiles)
    int b2 = b - 4096;
    src = s2; dst = d2; R = HDIM; C = ODIM;
    bx = b2 & 15; by = (b2 >> 4) & 31; e = b2 >> 9;
  }
  int c0 = bx * 64, r0g = by * 64;
  const float* s = src + (size_t)e * R * C;
#pragma unroll
  for (int p = 0; p < 4; p++) {
    int r = (tid >> 4) + p * 16;
    int c4 = (tid & 15) * 4;
    float4 v = *(const float4*)&s[(size_t)(r0g + r) * C + c0 + c4];
    t[r][c4 + 0] = v.x;
    t[r][c4 + 1] = v.y;
    t[r][c4 + 2] = v.z;
    t[r][c4 + 3] = v.w;
  }
  __syncthreads();
  bf16_t* d = dst + (size_t)e * R * C;
  int w = tid >> 6, l = tid & 63;
#pragma unroll
  for (int itc = 0; itc < 2; itc++) {
    int c = (l >> 3) + 8 * w + 32 * itc;
    int r0 = (l & 7) * 8;
    bf16x8 o;
#pragma unroll
    for (int j = 0; j < 8; j++) o[j] = (bf16_t)t[r0 + j][c];
    *(bf16x8*)&d[(size_t)(c0 + c) * R + r0g + r0] = o;
  }
}

// C[pos][n] = sum_k A[pos][k] * Bt[e][n][k] + bias[e][n]
// FROZEN round-4 structure (62.7us proven): BK=32, single 16KB buffer,
// stage -> barrier -> 16 MFMA -> barrier. All pipelining variants (2-phase
// dbuf, 8-phase counted-vmcnt, BK=64) measured 12-15% SLOWER: cross-block
// TLP at 4 blocks/CU already hides stage latency; extra LDS/regs only cost.
// XOR swizzle: staging lane loads global k-quarter (lane&3)^(row&3); LDS
// slot (row,qs) holds quarter qs^(row&3); fragment reads slot q^(mrow&3)
// -> ds_read_b128 conflict-free.
template <int KDIM, int NCOLS, int MTG, bool TO_BF16>
__global__ __launch_bounds__(256) void gemm_kernel(
    const bf16_t* __restrict__ A, const bf16_t* __restrict__ Bt,
    const float* __restrict__ bias,
    const int* __restrict__ cnt,
    const int* __restrict__ tok_of_pos,
    bf16_t* __restrict__ outb, float* __restrict__ outf) {
  constexpr int NT = NCOLS / 128;
  const int b = blockIdx.x;
  const int e = b & 7;
  int t = b >> 3;
  const int mtl = t % MTG;
  t /= MTG;
  const int nt = t % NT;
  const int g = t / NT;
  const int mt = g * MTG + mtl;

  int base, count;
  prefix_of(cnt, e, base, count);
  if (mt * 128 >= count) return;

  __shared__ bf16_t lA[128 * 32];
  __shared__ bf16_t lB[128 * 32];

  const int tid = threadIdx.x;
  const int lane = tid & 63;
  const int wave = tid >> 6;
  const int mrow = lane & 15;
  const int q = lane >> 4;
  const int wm = (wave & 1) * 64;
  const int wn = (wave >> 1) * 64;

  const bf16_t* pA[2];
  const bf16_t* pB[2];
#pragma unroll
  for (int s = 0; s < 2; s++) {
    int lrow = wave * 32 + s * 16 + (lane >> 2);
    int kq = (lane & 3) ^ (lrow & 3);
    int gr = base + mt * 128 + lrow;
    if (gr > NTOK - 1) gr = NTOK - 1;  // clamp: garbage rows masked at store
    pA[s] = A + (size_t)gr * KDIM + kq * 8;
    int nrow = nt * 128 + lrow;
    pB[s] = Bt + ((size_t)e * NCOLS + nrow) * KDIM + kq * 8;
  }

  f32x4 acc[4][4] = {};
  const bf16_t* la0 = &lA[(wm + mrow) * 32 + ((q ^ (mrow & 3)) * 8)];
  const bf16_t* lb0 = &lB[(wn + mrow) * 32 + ((q ^ (mrow & 3)) * 8)];

  for (int kk = 0; kk < KDIM; kk += 32) {
#pragma unroll
    for (int s = 0; s < 2; s++) {
      gld_lds16(&lA[(wave * 2 + s) * 512], pA[s] + kk);
      gld_lds16(&lB[(wave * 2 + s) * 512], pB[s] + kk);
    }
    __syncthreads();
    bf16x8 af[4], bfr[4];
#pragma unroll
    for (int i = 0; i < 4; i++) {
      af[i]  = *(const bf16x8*)(la0 + i * 16 * 32);
      bfr[i] = *(const bf16x8*)(lb0 + i * 16 * 32);
    }
#pragma unroll
    for (int i = 0; i < 4; i++)
#pragma unroll
      for (int j = 0; j < 4; j++)
        acc[i][j] = __builtin_amdgcn_mfma_f32_16x16x32_bf16(af[i], bfr[j], acc[i][j], 0, 0, 0);
    __syncthreads();
  }

  const int mlimit = count - mt * 128;
  float bs[4];
#pragma unroll
  for (int j = 0; j < 4; j++)
    bs[j] = bias[(size_t)e * NCOLS + nt * 128 + wn + j * 16 + mrow];

#pragma unroll
  for (int i = 0; i < 4; i++) {
#pragma unroll
    for (int r = 0; r < 4; r++) {
      int ml = wm + i * 16 + q * 4 + r;
      if (ml < mlimit) {
        int prow = base + mt * 128 + ml;
        if constexpr (TO_BF16) {
          bf16_t* orow = outb + (size_t)prow * NCOLS;
#pragma unroll
          for (int j = 0; j < 4; j++)
            orow[nt * 128 + wn + j * 16 + mrow] = (bf16_t)(acc[i][j][r] + bs[j]);
        } else {
          int tok = tok_of_pos[prow];
          float* orow = outf + (size_t)tok * OUTW;
#pragma unroll
          for (int j = 0; j < 4; j++)
            orow[nt * 128 + wn + j * 16 + mrow] = acc[i][j][r] + bs[j];
        }
      }
    }
  }
}

extern "C" void kernel_launch(void* const* d_in, const int* in_sizes, int n_in,
                              void* d_out, int out_size, void* d_ws, size_t ws_size,
                              hipStream_t stream) {
  const float* x  = (const float*)d_in[0];
  const float* W1 = (const float*)d_in[1];
  const float* b1 = (const float*)d_in[2];
  const float* W2 = (const float*)d_in[3];
  const float* b2 = (const float*)d_in[4];
  const int* idx  = (const int*)d_in[5];
  float* out = (float*)d_out;

  char* ws = (char*)d_ws;
  bf16_t* xg  = (bf16_t*)(ws);                 // 16 MB  [N][D] bf16
  bf16_t* hg  = (bf16_t*)(ws + 16777216);      // 32 MB  [N][H] bf16
  bf16_t* Wt1 = (bf16_t*)(ws + 50331648);      // 32 MB  [E][H][D] bf16
  bf16_t* Wt2 = (bf16_t*)(ws + 83886080);      // 32 MB  [E][O][H] bf16
  int* tok    = (int*)(ws + 117440512);        // 32 KB
  int* rank   = (int*)(ws + 117473280);        // 32 KB
  int* cnt    = (int*)(ws + 117506048);        // 32 B  (layout == round-4/5)

  // 5 dispatches: memset, route, prep (wtrans+gather), GEMM1, GEMM2.
  hipMemsetAsync(cnt, 0, NEXP * sizeof(int), stream);
  route_kernel<<<NTOK / 256, 256, 0, stream>>>(idx, out, rank, cnt);
  prep_kernel<<<WT_BLKS + GA_BLKS, 256, 0, stream>>>(x, idx, rank, cnt, xg, tok,
                                                     W1, Wt1, W2, Wt2);
  // GEMM1: K=1024, NCOLS=2048, MTG=8 (2MB A-group per XCD pass)
  gemm_kernel<DDIM, HDIM, 8, true>
      <<<NEXP * MT_MAX * (HDIM / 128), 256, 0, stream>>>(
      xg, Wt1, b1, cnt, tok, hg, nullptr);
  // GEMM2: K=2048, NCOLS=1024, MTG=4
  gemm_kernel<HDIM, ODIM, 4, false>
      <<<NEXP * MT_MAX * (ODIM / 128), 256, 0, stream>>>(
      hg, Wt2, b2, cnt, tok, nullptr, out);
}